// Round 15
// baseline (75.941 us; speedup 1.0000x reference)
//
#include <hip/hip_runtime.h>

// Problem constants (match reference)
#define BB 16
#define CC 8
#define HW (512 * 512)          // pixels per image
#define IGNORE_IDX 255
#define EPS_F 1e-5f
#define MINPIX 10.0f

// Launch config — 1024 blocks (exactly 4 resident per CU at VGPR<=128),
// 16 px/thread in 4 batches, explicit 2-deep software pipeline.
#define BPI 64                  // blocks per image
#define NTHR 256
#define NBLK (BB * BPI)         // 1024 stage-1 blocks
#define PPB (HW / BPI)          // 4096 pixels per block = 4 batches of 1024

// ws layout (floats):
//   [0      .. 8192)   inter[b][c][chunk]   (16*8*64)
//   [8192   .. 16384)  psum [b][c][chunk]
//   [16384  .. 24576)  tsum [b][c][chunk]
//   [24576  .. 25600)  ce_partial[block]
//   [25600  .. 26624)  cnt_partial[block]
// Every slot is rewritten by stage1 each call -> no init needed.
#define OFF_INTER 0
#define OFF_PSUM  8192
#define OFF_TSUM  16384
#define OFF_CE    24576
#define OFF_CNT   (24576 + NBLK)

__device__ __forceinline__ float wave_red(float v) {
#pragma unroll
    for (int o = 32; o > 0; o >>= 1) v += __shfl_xor(v, o, 64);
    return v;
}

// NOTE (R8): no min-waves hint — __launch_bounds__(256,3) forced VGPR 232->84
// via scratch spills (+440 MB spill traffic, 8x slower).
// NOTE (R9): compiler's full unroll = depth-4 pipeline at VGPR 232 -> occ 11%,
// 143 us. NOTE (R14): loop-free one-shot waves = one unhidden stall each,
// VALUBusy 25%, warm==cold 82 us. NOTE (R3/R11/R14): time grows ~8us per
// extra 1024 blocks -> keep grid at 1024.
// This version: manual depth-2 pipeline, two NAMED batches (A/B) so VGPR is
// bounded by construction (~115 <= 128 tier -> 4 waves/SIMD).
// NOTE (R7/R12): fusion closed (fence storm / atomic serialization).
__global__ __launch_bounds__(NTHR) void focal_stage1(
    const float* __restrict__ logits, const int* __restrict__ tgt,
    float* __restrict__ ws)
{
    const int b     = blockIdx.x / BPI;
    const int chunk = blockIdx.x % BPI;
    const float* base = logits + (size_t)b * (CC * HW);
    const int*   tb   = tgt    + (size_t)b * HW;
    const int start = chunk * PPB + (int)threadIdx.x * 4;

    float psum[8]  = {0.f,0.f,0.f,0.f,0.f,0.f,0.f,0.f};
    float inter[8] = {0.f,0.f,0.f,0.f,0.f,0.f,0.f,0.f};
    int   tcnt[8]  = {0,0,0,0,0,0,0,0};
    float ce = 0.f;
    int   cnt = 0;

    int4   tA, tB;
    float4 vA[8], vB[8];

    auto LOADB = [&](int it, int4& t4, float4 (&v)[8]) {
        const int pix = start + it * (NTHR * 4);
        t4 = *reinterpret_cast<const int4*>(tb + pix);
#pragma unroll
        for (int c = 0; c < 8; ++c)
            v[c] = *reinterpret_cast<const float4*>(base + (size_t)c * HW + pix);
    };

    auto COMPUTE = [&](const int4& t4, const float4 (&v)[8]) {
#pragma unroll
        for (int j = 0; j < 4; ++j) {
            const int t = (&t4.x)[j];
            float x[8];
#pragma unroll
            for (int c = 0; c < 8; ++c) x[c] = (&v[c].x)[j];

            float m = x[0];
#pragma unroll
            for (int c = 1; c < 8; ++c) m = fmaxf(m, x[c]);

            float e[8];
            float s = 0.f;
#pragma unroll
            for (int c = 0; c < 8; ++c) { e[c] = __expf(x[c] - m); s += e[c]; }
            const float inv = 1.0f / s;

            const bool valid = (t != IGNORE_IDX);
            float xt = 0.f, et = 0.f;
#pragma unroll
            for (int c = 0; c < 8; ++c) {
                const float pc = e[c] * inv;
                psum[c] += valid ? pc : 0.f;
                const bool hit = valid && (t == c);
                inter[c] += hit ? pc : 0.f;
                tcnt[c]  += hit ? 1 : 0;
                xt = (t == c) ? x[c] : xt;   // compile-time-unrolled select
                et = (t == c) ? e[c] : et;
            }
            const float pt    = et * inv;
            const float logpt = (xt - m) - __logf(s);
            const float omp   = 1.f - pt;
            ce  += valid ? -(omp * omp) * logpt : 0.f;
            cnt += valid ? 1 : 0;
        }
    };

    // 2-deep pipeline over 4 batches: each batch's loads issue one full
    // compute-phase before their use.
    LOADB(0, tA, vA);
    LOADB(1, tB, vB);
    COMPUTE(tA, vA);
    LOADB(2, tA, vA);
    COMPUTE(tB, vB);
    LOADB(3, tB, vB);
    COMPUTE(tA, vA);
    COMPUTE(tB, vB);

    // ---- block reduction: wave shuffle -> LDS -> single write per value ----
    __shared__ float sm[4][26];
    const int wave = threadIdx.x >> 6;
    const int lane = threadIdx.x & 63;

    float red[26];
#pragma unroll
    for (int c = 0; c < 8; ++c) red[c]      = inter[c];
#pragma unroll
    for (int c = 0; c < 8; ++c) red[8 + c]  = psum[c];
#pragma unroll
    for (int c = 0; c < 8; ++c) red[16 + c] = (float)tcnt[c];
    red[24] = ce;
    red[25] = (float)cnt;

#pragma unroll
    for (int k = 0; k < 26; ++k) {
        const float r = wave_red(red[k]);
        if (lane == 0) sm[wave][k] = r;
    }
    __syncthreads();

    const int tid = threadIdx.x;
    if (tid < 26) {
        const float tot = sm[0][tid] + sm[1][tid] + sm[2][tid] + sm[3][tid];
        if (tid < 8)
            ws[OFF_INTER + ((b * CC + tid) * BPI) + chunk] = tot;
        else if (tid < 16)
            ws[OFF_PSUM + ((b * CC + (tid - 8)) * BPI) + chunk] = tot;
        else if (tid < 24)
            ws[OFF_TSUM + ((b * CC + (tid - 16)) * BPI) + chunk] = tot;
        else if (tid == 24)
            ws[OFF_CE + blockIdx.x] = tot;
        else
            ws[OFF_CNT + blockIdx.x] = tot;
    }
}

// Stage 2: 1 block x 1024 threads, float4 reads, shuffle folds.
#define NTHR2 1024

__global__ __launch_bounds__(NTHR2) void focal_stage2(
    const float* __restrict__ ws, float* __restrict__ out)
{
    const int tid  = threadIdx.x;
    const int wave = tid >> 6;
    const int lane = tid & 63;

    // ---- dice: pair = b*CC+c (128), 8 subthreads each sum 8 chunks (f4 x2)
    const int pair = tid >> 3;            // 0..127
    const int sub  = tid & 7;
    float I = 0.f, P = 0.f, T = 0.f;
    {
        const int off = pair * BPI + sub * (BPI / 8);   // 8 floats, 16B aligned
#pragma unroll
        for (int k = 0; k < BPI / 8; k += 4) {
            const float4 i4 = *reinterpret_cast<const float4*>(&ws[OFF_INTER + off + k]);
            const float4 p4 = *reinterpret_cast<const float4*>(&ws[OFF_PSUM  + off + k]);
            const float4 t4 = *reinterpret_cast<const float4*>(&ws[OFF_TSUM  + off + k]);
            I += i4.x + i4.y + i4.z + i4.w;
            P += p4.x + p4.y + p4.z + p4.w;
            T += t4.x + t4.y + t4.z + t4.w;
        }
    }
#pragma unroll
    for (int o = 1; o < 8; o <<= 1) {     // combine the 8 subthreads (same wave)
        I += __shfl_xor(I, o, 64);
        P += __shfl_xor(P, o, 64);
        T += __shfl_xor(T, o, 64);
    }

    float dval = 0.f;
    const int c = pair & 7;
    if (sub == 0 && c >= 1 && T > MINPIX)
        dval = 1.f - (2.f * I + EPS_F) / (P + T + EPS_F);

    // ---- ce partials: 1024 floats each; threads 0..255 read one float4 ----
    float ce = 0.f, cn = 0.f;
    if (tid < NBLK / 4) {
        const float4 c4 = *reinterpret_cast<const float4*>(&ws[OFF_CE  + tid * 4]);
        const float4 n4 = *reinterpret_cast<const float4*>(&ws[OFF_CNT + tid * 4]);
        ce = c4.x + c4.y + c4.z + c4.w;
        cn = n4.x + n4.y + n4.z + n4.w;
    }

    dval = wave_red(dval);
    ce   = wave_red(ce);
    cn   = wave_red(cn);

    __shared__ float sd[3][16];
    if (lane == 0) { sd[0][wave] = dval; sd[1][wave] = ce; sd[2][wave] = cn; }
    __syncthreads();

    if (tid == 0) {
        float D = 0.f, CE = 0.f, CN = 0.f;
#pragma unroll
        for (int w = 0; w < 16; ++w) { D += sd[0][w]; CE += sd[1][w]; CN += sd[2][w]; }
        out[0] = (CE / CN) + 0.1f * (D / ((CC - 1) * (float)BB));
    }
}

extern "C" void kernel_launch(void* const* d_in, const int* in_sizes, int n_in,
                              void* d_out, int out_size, void* d_ws, size_t ws_size,
                              hipStream_t stream)
{
    const float* logits = (const float*)d_in[0];
    const int*   tgt    = (const int*)d_in[1];
    float*       ws     = (float*)d_ws;
    float*       out    = (float*)d_out;

    focal_stage1<<<NBLK, NTHR, 0, stream>>>(logits, tgt, ws);
    focal_stage2<<<1, NTHR2, 0, stream>>>(ws, out);
}